// Round 8
// baseline (155.148 us; speedup 1.0000x reference)
//
#include <hip/hip_runtime.h>

typedef _Float16 f16;
typedef _Float16 f16x8 __attribute__((ext_vector_type(8)));
typedef _Float16 f16x4 __attribute__((ext_vector_type(4)));
typedef _Float16 f16x2 __attribute__((ext_vector_type(2)));
typedef float f32x4 __attribute__((ext_vector_type(4)));

#define MFMA(a, b, c) __builtin_amdgcn_mfma_f32_16x16x32_f16(a, b, c, 0, 0, 0)
#define PKRTZ(a, b) __builtin_bit_cast(f16x2, __builtin_amdgcn_cvt_pkrtz(a, b))

__device__ __forceinline__ void gload16(const void* g, void* l) {
  __builtin_amdgcn_global_load_lds((const __attribute__((address_space(1))) char*)g,
                                   (__attribute__((address_space(3))) char*)l, 16, 0, 0);
}

// B=2, T=2048, D=1024, H=16, DH=64

// ---------- prep: z<4: transpose+convert weight z; z==4: fp32->fp16 hidden ----------
__global__ __launch_bounds__(256) void k_prep(const float* __restrict__ hid,
                                              const float* __restrict__ w0, const float* __restrict__ w1,
                                              const float* __restrict__ w2, const float* __restrict__ w3,
                                              f16* __restrict__ aH, f16* __restrict__ wt) {
  int z = blockIdx.z;
  int t = threadIdx.x;
  if (z == 4) {
    int base = (blockIdx.y * 16 + blockIdx.x) * 256 + t;
#pragma unroll
    for (int j = 0; j < 16; j++) {
      int i = base + j * 65536;
      float4 v = ((const float4*)hid)[i];
      f16x4 h; h[0] = (f16)v.x; h[1] = (f16)v.y; h[2] = (f16)v.z; h[3] = (f16)v.w;
      ((f16x4*)aH)[i] = h;
    }
    return;
  }
  const float* w = z == 0 ? w0 : z == 1 ? w1 : z == 2 ? w2 : w3;
  f16* dst = wt + (size_t)z * 1024 * 1024;
  __shared__ float tile[64][65];
  int k0 = blockIdx.x * 64, n0 = blockIdx.y * 64;
  int cr = t >> 4, cc = (t & 15) * 4;
#pragma unroll
  for (int p = 0; p < 4; p++) {
    int r = cr + p * 16;
    float4 v = *(const float4*)&w[(size_t)(k0 + r) * 1024 + n0 + cc];
    tile[r][cc + 0] = v.x; tile[r][cc + 1] = v.y; tile[r][cc + 2] = v.z; tile[r][cc + 3] = v.w;
  }
  __syncthreads();
#pragma unroll
  for (int p = 0; p < 4; p++) {
    int nn = cr + p * 16;
    f16x4 h;
    h[0] = (f16)tile[cc + 0][nn]; h[1] = (f16)tile[cc + 1][nn];
    h[2] = (f16)tile[cc + 2][nn]; h[3] = (f16)tile[cc + 3][nn];
    *(f16x4*)&dst[(size_t)(n0 + nn) * 1024 + k0 + cc] = h;
  }
}

// ---------- QKV GEMM: C[128 rows][128 cols] = A @ Wrows^T, double-buffered DMA staging ----------
__device__ __forceinline__ void gemm_core(const f16* __restrict__ A, const f16* __restrict__ Wrows,
                                          const float* __restrict__ bias, int m0,
                                          f16* __restrict__ oh) {
  __shared__ f16 Al[2][128 * 64];
  __shared__ f16 Bl[2][128 * 64];
  const int t = threadIdx.x;
  const int lane = t & 63, wid = t >> 6;
  const int lr = lane & 15, lg = lane >> 4;
  const int wm = wid >> 1, wn = wid & 1;
  const int lrow = lane >> 3;
  const int cb = (((lane & 7) ^ lrow) << 4);        // pre-swizzled source byte col

  f32x4 acc[4][4] = {};

  auto stage = [&](int k0, int bs) {
#pragma unroll
    for (int it = 0; it < 4; it++) {
      int rbase = it * 32 + wid * 8;                // wave-uniform
      int row = rbase + lrow;
      gload16((const char*)&A[(size_t)(m0 + row) * 1024 + k0] + cb, (char*)&Al[bs][0] + rbase * 128);
      gload16((const char*)&Wrows[(size_t)row * 1024 + k0] + cb, (char*)&Bl[bs][0] + rbase * 128);
    }
  };

  stage(0, 0);
  __syncthreads();
  int cur = 0;
  for (int k0 = 0; k0 < 1024; k0 += 64) {
    if (k0 + 64 < 1024) stage(k0 + 64, cur ^ 1);
    f16x8 af[2][4], bf[2][4];
#pragma unroll
    for (int x = 0; x < 4; x++) {
      int ra = wm * 64 + x * 16 + lr;
      int rb = wn * 64 + x * 16 + lr;
#pragma unroll
      for (int kh = 0; kh < 2; kh++) {
        int ca = (kh * 64 + lg * 16) ^ ((lr & 7) << 4);
        af[kh][x] = *(const f16x8*)((char*)&Al[cur][0] + ra * 128 + ca);
        bf[kh][x] = *(const f16x8*)((char*)&Bl[cur][0] + rb * 128 + ca);
      }
    }
    __builtin_amdgcn_s_setprio(1);
#pragma unroll
    for (int kh = 0; kh < 2; kh++)
#pragma unroll
      for (int mt = 0; mt < 4; mt++)
#pragma unroll
        for (int nt = 0; nt < 4; nt++)
          acc[mt][nt] = MFMA(af[kh][mt], bf[kh][nt], acc[mt][nt]);
    __builtin_amdgcn_s_setprio(0);
    __syncthreads();
    cur ^= 1;
  }
#pragma unroll
  for (int mt = 0; mt < 4; mt++) {
#pragma unroll
    for (int nt = 0; nt < 4; nt++) {
      int col = wn * 64 + nt * 16 + lr;             // local 0..127
      float bcol = bias[col];
#pragma unroll
      for (int e = 0; e < 4; e++) {
        int row = m0 + wm * 64 + mt * 16 + lg * 4 + e;
        oh[(size_t)row * 1024 + col] = (f16)(acc[mt][nt][e] + bcol);
      }
    }
  }
}

// fused QKV: W' = wt as [3072][1024]; grid (32, 24)
__global__ __launch_bounds__(256, 2) void k_gemm_qkv(const f16* __restrict__ A, const f16* __restrict__ wt,
                                                     const float* __restrict__ bq, const float* __restrict__ bk,
                                                     const float* __restrict__ bv,
                                                     f16* __restrict__ q, f16* __restrict__ k, f16* __restrict__ v) {
  int n0 = blockIdx.y * 128;
  int zsel = n0 >> 10, cbs = n0 & 1023;
  const float* bias = (zsel == 0 ? bq : zsel == 1 ? bk : bv) + cbs;
  f16* dst = (zsel == 0 ? q : zsel == 1 ? k : v) + cbs;
  gemm_core(A, wt + (size_t)n0 * 1024, bias, blockIdx.x * 128, dst);
}

// ---------- O-GEMM with fused split-KV merge in A-staging ----------
// A[row][k] = w0(row,head)*op0 + w1(row,head)*op1, head = k0/64 (BK == DH == 64).
// A: reg-staged (load early, merge+ds_write late); B: global_load_lds.
__global__ __launch_bounds__(256, 2) void k_gemm_o(const f16* __restrict__ op0, const f16* __restrict__ op1,
                                                   const float* __restrict__ ml,
                                                   const f16* __restrict__ wt3,
                                                   const float* __restrict__ bo, float* __restrict__ out) {
  __shared__ f16 Al[2][128 * 64];
  __shared__ f16 Bl[2][128 * 64];
  const int t = threadIdx.x;
  const int lane = t & 63, wid = t >> 6;
  const int lr = lane & 15, lg = lane >> 4;
  const int wm = wid >> 1, wn = wid & 1;
  const int lrow = lane >> 3;
  const int cb = (((lane & 7) ^ lrow) << 4);
  const int m0 = blockIdx.x * 128, n0 = blockIdx.y * 128;
  const f16* Wrows = wt3 + (size_t)n0 * 1024;
  const float* bias = bo + n0;
  float* of = out + n0;

  f32x4 acc[4][4] = {};
  f16x8 a0r[4], a1r[4];
  float2 ml0r[4], ml1r[4];

  auto stageB = [&](int k0, int bs) {
#pragma unroll
    for (int it = 0; it < 4; it++) {
      int rbase = it * 32 + wid * 8;
      gload16((const char*)&Wrows[(size_t)(rbase + lrow) * 1024 + k0] + cb, (char*)&Bl[bs][0] + rbase * 128);
    }
  };
  auto loadA = [&](int k0) {
    int head = k0 >> 6;
#pragma unroll
    for (int it = 0; it < 4; it++) {
      int rg = m0 + it * 32 + wid * 8 + lrow;
      size_t off = (size_t)rg * 1024 + k0 + (cb >> 1);
      a0r[it] = *(const f16x8*)&op0[off];
      a1r[it] = *(const f16x8*)&op1[off];
      int qid = (((rg >> 11) << 4) + head) * 2048 + (rg & 2047);
      ml0r[it] = *(const float2*)&ml[(size_t)qid * 2];
      ml1r[it] = *(const float2*)&ml[(size_t)(65536 + qid) * 2];
    }
  };
  auto writeA = [&](int bs) {
#pragma unroll
    for (int it = 0; it < 4; it++) {
      float mm = fmaxf(ml0r[it].x, ml1r[it].x);
      float w0 = ml0r[it].y * exp2f(ml0r[it].x - mm);
      float w1 = ml1r[it].y * exp2f(ml1r[it].x - mm);
      float inv = 1.f / (w0 + w1);
      w0 *= inv; w1 *= inv;
      f16x8 o;
#pragma unroll
      for (int j = 0; j < 8; j++)
        o[j] = (f16)(w0 * (float)a0r[it][j] + w1 * (float)a1r[it][j]);
      int rbase = it * 32 + wid * 8;
      *(f16x8*)((char*)&Al[bs][0] + (rbase + lrow) * 128 + (lane & 7) * 16) = o;
    }
  };

  loadA(0); stageB(0, 0); writeA(0);
  __syncthreads();
  int cur = 0;
  for (int k0 = 0; k0 < 1024; k0 += 64) {
    bool pre = (k0 + 64 < 1024);
    if (pre) { loadA(k0 + 64); stageB(k0 + 64, cur ^ 1); }
    f16x8 af[2][4], bf[2][4];
#pragma unroll
    for (int x = 0; x < 4; x++) {
      int ra = wm * 64 + x * 16 + lr;
      int rb = wn * 64 + x * 16 + lr;
#pragma unroll
      for (int kh = 0; kh < 2; kh++) {
        int ca = (kh * 64 + lg * 16) ^ ((lr & 7) << 4);
        af[kh][x] = *(const f16x8*)((char*)&Al[cur][0] + ra * 128 + ca);
        bf[kh][x] = *(const f16x8*)((char*)&Bl[cur][0] + rb * 128 + ca);
      }
    }
    __builtin_amdgcn_s_setprio(1);
#pragma unroll
    for (int kh = 0; kh < 2; kh++)
#pragma unroll
      for (int mt = 0; mt < 4; mt++)
#pragma unroll
        for (int nt = 0; nt < 4; nt++)
          acc[mt][nt] = MFMA(af[kh][mt], bf[kh][nt], acc[mt][nt]);
    __builtin_amdgcn_s_setprio(0);
    if (pre) writeA(cur ^ 1);     // merge in the MFMA shadow; target buffer not in use
    __syncthreads();
    cur ^= 1;
  }
#pragma unroll
  for (int mt = 0; mt < 4; mt++) {
#pragma unroll
    for (int nt = 0; nt < 4; nt++) {
      int col = wn * 64 + nt * 16 + lr;
      float bcol = bias[col];
#pragma unroll
      for (int e = 0; e < 4; e++) {
        int row = m0 + wm * 64 + mt * 16 + lg * 4 + e;
        of[(size_t)row * 1024 + col] = acc[mt][nt][e] + bcol;
      }
    }
  }
}

// ---------- fused: y<2: RMSNorm+RoPE on q/k; y==2: V transpose ----------
__global__ __launch_bounds__(256) void k_nrv(f16* __restrict__ qh, f16* __restrict__ kh,
                                             const float* __restrict__ gq, const float* __restrict__ gk,
                                             const float* __restrict__ cs, const float* __restrict__ sn,
                                             const f16* __restrict__ vh, f16* __restrict__ vt) {
  __shared__ float redtile[64][65];   // vtrans tile (reused as f32 for alignment)
  int which = blockIdx.y;
  int t = threadIdx.x;
  if (which == 2) {
    if (blockIdx.x >= 1024) return;
    f16* tile = (f16*)&redtile[0][0];  // [64][66] f16 view (pad 2 per row)
    int bh = blockIdx.x & 31;
    int t0 = (blockIdx.x >> 5) * 64;
    int b = bh >> 4, h = bh & 15;
    int rr = t >> 3, c8 = (t & 7) * 8;
#pragma unroll
    for (int p = 0; p < 2; p++) {
      int r = p * 32 + rr;
      f16x8 v = *(const f16x8*)&vh[(size_t)(b * 2048 + t0 + r) * 1024 + h * 64 + c8];
#pragma unroll
      for (int j = 0; j < 8; j++) tile[r * 66 + c8 + j] = v[j];
    }
    __syncthreads();
#pragma unroll
    for (int p = 0; p < 2; p++) {
      int dh = p * 32 + rr;
      f16x8 o;
#pragma unroll
      for (int j = 0; j < 8; j++) o[j] = tile[(c8 + j) * 66 + dh];
      *(f16x8*)&vt[((size_t)bh * 64 + dh) * 2048 + t0 + c8] = o;
    }
    return;
  }
  int row = blockIdx.x;
  f16* buf = which ? kh : qh;
  const float* g = which ? gk : gq;
  int c4 = t * 4;
  f16x4 xv = *(const f16x4*)&buf[(size_t)row * 1024 + c4];
  float x0 = xv[0], x1 = xv[1], x2 = xv[2], x3 = xv[3];
  float ss = x0 * x0 + x1 * x1 + x2 * x2 + x3 * x3;
#pragma unroll
  for (int off = 1; off < 64; off <<= 1) ss += __shfl_xor(ss, off);
  float* red = &redtile[0][0];
  if ((t & 63) == 0) red[t >> 6] = ss;
  __syncthreads();
  float inv = rsqrtf((red[0] + red[1] + red[2] + red[3]) * (1.0f / 1024.0f) + 1e-6f);
  int tt = row & 2047;
  float4 cv = *(const float4*)&cs[(size_t)tt * 1024 + c4];
  float4 sv = *(const float4*)&sn[(size_t)tt * 1024 + c4];
  float4 gv = *(const float4*)&g[c4];
  float y0 = x0 * inv * gv.x, y1 = x1 * inv * gv.y, y2 = x2 * inv * gv.z, y3 = x3 * inv * gv.w;
  f16x4 ov;
  ov[0] = (f16)(y0 * cv.x - y1 * sv.x);
  ov[1] = (f16)(y1 * cv.y + y0 * sv.y);
  ov[2] = (f16)(y2 * cv.z - y3 * sv.z);
  ov[3] = (f16)(y3 * cv.w + y2 * sv.w);
  *(f16x4*)&buf[(size_t)row * 1024 + c4] = ov;
}

// ---------- flash attention: split-KV x2, 32 q/wave, ones-column row-sum ----------
// grid 1024: raw&7 = XCD (4 bh per XCD), (raw>>5)&1 = KV half, raw>>6 = q-block.
#define ASWZ(row) ((((row) & 3) | (((row) & 8) >> 1)) << 4)

__global__ __launch_bounds__(256, 4) void k_attn(const f16* __restrict__ qh, const f16* __restrict__ kh,
                                                 const f16* __restrict__ vt,
                                                 f16* __restrict__ op0, f16* __restrict__ op1,
                                                 float* __restrict__ ml) {
  __shared__ f16 Kl[2][64 * 64];
  __shared__ f16 Vl[2][64 * 64];
  const int t = threadIdx.x;
  const int lane = t & 63, wid = t >> 6;
  const int lr = lane & 15, lg = lane >> 4;
  const int lgb = lg << 4;
  const int raw = blockIdx.x;
  const int mybh = ((raw & 7) << 2) | ((raw >> 3) & 3);
  const int half = (raw >> 5) & 1;
  const int myq = raw >> 6;                   // [0,16)
  const int b = mybh >> 4, h = mybh & 15;
  const int q0 = myq * 128 + wid * 32;
  const int kvbase = half << 10;              // 0 or 1024
  f16* __restrict__ op = half ? op1 : op0;
  const f16* Qb = qh + ((size_t)(b * 2048 + q0)) * 1024 + h * 64;
  f16x8 qf[2][2];
#pragma unroll
  for (int g = 0; g < 2; g++) {
    qf[g][0] = *(const f16x8*)&Qb[(size_t)(g * 16 + lr) * 1024 + lg * 8];
    qf[g][1] = *(const f16x8*)&Qb[(size_t)(g * 16 + lr) * 1024 + 32 + lg * 8];
  }
  const f16* Kg = kh + ((size_t)b * 2048) * 1024 + h * 64;
  const f16* Vg = vt + ((size_t)mybh) * 64 * 2048;
  const int lrow = lane >> 3;
  const int sg = (lane & 7) << 4;
  const float sc = 0.125f * 1.44269504088896340736f;
  float m[2] = {-1e30f, -1e30f};
  f32x4 acc[2][4] = {};
  f32x4 accl[2] = {};
  const f16 ov1 = (lr == 0) ? (f16)1.0f : (f16)0.0f;
  const f16x8 onesf = {ov1, ov1, ov1, ov1, ov1, ov1, ov1, ov1};

  auto stage = [&](int kvo, int bs) {
#pragma unroll
    for (int i = 0; i < 2; i++) {
      int rbase = (i * 4 + wid) * 8;          // wave-uniform
      int row = rbase + lrow;
      int cswz = sg ^ ASWZ(row);
      gload16((const char*)(Kg + (size_t)(kvo + row) * 1024) + cswz, (char*)&Kl[bs][0] + rbase * 128);
      gload16((const char*)(Vg + (size_t)row * 2048 + kvo) + cswz, (char*)&Vl[bs][0] + rbase * 128);
    }
  };

  stage(kvbase, 0);
  __syncthreads();
  int cur = 0;

  for (int c = 0; c < 16; c++) {
    int kv0 = kvbase + c * 64;
    if (c + 1 < 16) stage(kv0 + 64, cur ^ 1);
    const char* Kb = (const char*)&Kl[cur][0];
    const char* Vb = (const char*)&Vl[cur][0];

    f32x4 s[2][4];
    __builtin_amdgcn_s_setprio(1);
#pragma unroll
    for (int ks = 0; ks < 4; ks++) {
      int key = ((lr >> 2) << 3) + (lr & 3) + ((ks & 1) << 2) + ((ks >> 1) << 5);
      int sw = ASWZ(key);
      f16x8 kf0 = *(const f16x8*)(Kb + key * 128 + (lgb ^ sw));
      f16x8 kf1 = *(const f16x8*)(Kb + key * 128 + ((64 + lgb) ^ sw));
#pragma unroll
      for (int g = 0; g < 2; g++) {
        f32x4 z = {};
        z = MFMA(kf0, qf[g][0], z);
        z = MFMA(kf1, qf[g][1], z);
        s[g][ks] = z;
      }
    }
    __builtin_amdgcn_s_setprio(0);

    union U { f16x8 v; f16x2 h[4]; } u[2][2];
#pragma unroll
    for (int g = 0; g < 2; g++) {
      float smax = fmaxf(fmaxf(s[g][0][0], s[g][0][1]), s[g][0][2]);
      smax = fmaxf(fmaxf(smax, s[g][0][3]), s[g][1][0]);
      smax = fmaxf(fmaxf(smax, s[g][1][1]), s[g][1][2]);
      smax = fmaxf(fmaxf(smax, s[g][1][3]), s[g][2][0]);
      smax = fmaxf(fmaxf(smax, s[g][2][1]), s[g][2][2]);
      smax = fmaxf(fmaxf(smax, s[g][2][3]), s[g][3][0]);
      smax = fmaxf(fmaxf(smax, s[g][3][1]), s[g][3][2]);
      smax = fmaxf(smax, s[g][3][3]);
      smax = fmaxf(smax, __shfl_xor(smax, 16));
      smax = fmaxf(smax, __shfl_xor(smax, 32));
      float smc = smax * sc;

      if (!__all(smc - m[g] <= 8.f)) {        // defer-max
        float mn = fmaxf(m[g], smc);
        float al = exp2f(m[g] - mn);
        m[g] = mn;
        float alq[4];
#pragma unroll
        for (int e = 0; e < 4; e++) alq[e] = __shfl(al, lg * 4 + e);
#pragma unroll
        for (int ds = 0; ds < 4; ds++)
#pragma unroll
          for (int e = 0; e < 4; e++) acc[g][ds][e] *= alq[e];
#pragma unroll
        for (int e = 0; e < 4; e++) accl[g][e] *= alq[e];
      }

#pragma unroll
      for (int ks = 0; ks < 4; ks++) {
        float p0 = exp2f(fmaf(s[g][ks][0], sc, -m[g]));
        float p1 = exp2f(fmaf(s[g][ks][1], sc, -m[g]));
        float p2 = exp2f(fmaf(s[g][ks][2], sc, -m[g]));
        float p3 = exp2f(fmaf(s[g][ks][3], sc, -m[g]));
        u[g][ks >> 1].h[(ks & 1) * 2 + 0] = PKRTZ(p0, p1);
        u[g][ks >> 1].h[(ks & 1) * 2 + 1] = PKRTZ(p2, p3);
      }
    }

    __builtin_amdgcn_s_setprio(1);
#pragma unroll
    for (int ds = 0; ds < 4; ds++) {
      int vrow = ds * 16 + lr;
      int sw = ASWZ(vrow);
      f16x8 vf0 = *(const f16x8*)(Vb + vrow * 128 + (lgb ^ sw));
      f16x8 vf1 = *(const f16x8*)(Vb + vrow * 128 + ((64 + lgb) ^ sw));
#pragma unroll
      for (int g = 0; g < 2; g++) {
        acc[g][ds] = MFMA(u[g][0].v, vf0, acc[g][ds]);
        acc[g][ds] = MFMA(u[g][1].v, vf1, acc[g][ds]);
      }
    }
#pragma unroll
    for (int g = 0; g < 2; g++) {
      accl[g] = MFMA(u[g][0].v, onesf, accl[g]);
      accl[g] = MFMA(u[g][1].v, onesf, accl[g]);
    }
    __builtin_amdgcn_s_setprio(0);

    __syncthreads();
    cur ^= 1;
  }

  // epilogue: normalized partial O + (m, l) per q-row
#pragma unroll
  for (int g = 0; g < 2; g++) {
    int qglob = mybh * 2048 + q0 + g * 16;
    if (lg == 0)
      ml[(size_t)((half << 16) + qglob + lr) * 2 + 0] = m[g];
    if (lr == 0) {
#pragma unroll
      for (int e = 0; e < 4; e++)
        ml[(size_t)((half << 16) + qglob + lg * 4 + e) * 2 + 1] = accl[g][e];
    }
#pragma unroll
    for (int e = 0; e < 4; e++) {
      float lf = 1.f / __shfl(accl[g][e], lg << 4);
      size_t row = (size_t)(b * 2048 + q0 + g * 16 + lg * 4 + e);
#pragma unroll
      for (int ds = 0; ds < 4; ds++)
        op[row * 1024 + h * 64 + ds * 16 + lr] = (f16)(acc[g][ds][e] * lf);
    }
  }
}

extern "C" void kernel_launch(void* const* d_in, const int* in_sizes, int n_in,
                              void* d_out, int out_size, void* d_ws, size_t ws_size,
                              hipStream_t stream) {
  const float* hid  = (const float*)d_in[0];
  const float* cosb = (const float*)d_in[1];
  const float* sinb = (const float*)d_in[2];
  const float* wq = (const float*)d_in[3];
  const float* bq = (const float*)d_in[4];
  const float* wk = (const float*)d_in[5];
  const float* bk = (const float*)d_in[6];
  const float* wv = (const float*)d_in[7];
  const float* bv = (const float*)d_in[8];
  const float* gq = (const float*)d_in[9];
  const float* gk = (const float*)d_in[10];
  const float* wo = (const float*)d_in[11];
  const float* bo = (const float*)d_in[12];
  float* out = (float*)d_out;

  char* ws = (char*)d_ws;
  f16* aH  = (f16*)(ws);                          // 8 MB: hidden fp16; reused as op1 after QKV
  f16* wt  = (f16*)(ws + ((size_t)8 << 20));      // 8 MB: 4 weights transposed [n][k] fp16
  f16* qh  = (f16*)(ws + ((size_t)16 << 20));     // 8 MB
  f16* khb = (f16*)(ws + ((size_t)24 << 20));     // 8 MB
  f16* vhb = (f16*)(ws + ((size_t)32 << 20));     // 8 MB: V; reused as op0 after vtrans
  f16* vtb = (f16*)(ws + ((size_t)40 << 20));     // 8 MB: V^T [b,h,dh,t]
  float* ml = (float*)(ws + ((size_t)48 << 20));  // 1 MB: [2][65536][m,l] f32

  k_prep<<<dim3(16, 16, 5), dim3(256), 0, stream>>>(hid, wq, wk, wv, wo, aH, wt);
  k_gemm_qkv<<<dim3(32, 24), dim3(256), 0, stream>>>(aH, wt, bq, bk, bv, qh, khb, vhb);
  k_nrv<<<dim3(4096, 3), dim3(256), 0, stream>>>(qh, khb, gq, gk, cosb, sinb, vhb, vtb);
  k_attn<<<dim3(1024), dim3(256), 0, stream>>>(qh, khb, vtb, /*op0=*/vhb, /*op1=*/aH, ml);
  k_gemm_o<<<dim3(32, 8), dim3(256), 0, stream>>>(vhb, aH, ml, wt + (size_t)3 * 1024 * 1024, bo, out);
}

// Round 9
// 142.807 us; speedup vs baseline: 1.0864x; 1.0864x over previous
//
#include <hip/hip_runtime.h>

typedef _Float16 f16;
typedef _Float16 f16x8 __attribute__((ext_vector_type(8)));
typedef _Float16 f16x4 __attribute__((ext_vector_type(4)));
typedef _Float16 f16x2 __attribute__((ext_vector_type(2)));
typedef float f32x4 __attribute__((ext_vector_type(4)));

#define MFMA(a, b, c) __builtin_amdgcn_mfma_f32_16x16x32_f16(a, b, c, 0, 0, 0)
#define PKRTZ(a, b) __builtin_bit_cast(f16x2, __builtin_amdgcn_cvt_pkrtz(a, b))
#define BARRAW() do { asm volatile("" ::: "memory"); __builtin_amdgcn_s_barrier(); asm volatile("" ::: "memory"); } while (0)
#define WAITLGKM0() do { asm volatile("s_waitcnt lgkmcnt(0)" ::: "memory"); __builtin_amdgcn_sched_barrier(0); } while (0)

__device__ __forceinline__ void gload16(const void* g, void* l) {
  __builtin_amdgcn_global_load_lds((const __attribute__((address_space(1))) char*)g,
                                   (__attribute__((address_space(3))) char*)l, 16, 0, 0);
}

// B=2, T=2048, D=1024, H=16, DH=64

// ---------- prep: fp32 -> fp16 convert of hidden ----------
__global__ __launch_bounds__(256) void k_cvt_hidden(const float* __restrict__ x, f16* __restrict__ y) {
  int i = blockIdx.x * 256 + threadIdx.x;
  float4 v = ((const float4*)x)[i];
  f16x4 h; h[0] = (f16)v.x; h[1] = (f16)v.y; h[2] = (f16)v.z; h[3] = (f16)v.w;
  ((f16x4*)y)[i] = h;
}

// ---------- prep: transpose+convert weights [k][n] fp32 -> [n][k] fp16 ----------
__global__ __launch_bounds__(256) void k_cvt_w(const float* __restrict__ w0, const float* __restrict__ w1,
                                               const float* __restrict__ w2, const float* __restrict__ w3,
                                               f16* __restrict__ wt) {
  int z = blockIdx.z;
  const float* w = z == 0 ? w0 : z == 1 ? w1 : z == 2 ? w2 : w3;
  f16* dst = wt + (size_t)z * 1024 * 1024;
  __shared__ float tile[64][65];
  int t = threadIdx.x;
  int k0 = blockIdx.x * 64, n0 = blockIdx.y * 64;
  int cr = t >> 4, cc = (t & 15) * 4;
#pragma unroll
  for (int p = 0; p < 4; p++) {
    int r = cr + p * 16;
    float4 v = *(const float4*)&w[(size_t)(k0 + r) * 1024 + n0 + cc];
    tile[r][cc + 0] = v.x; tile[r][cc + 1] = v.y; tile[r][cc + 2] = v.z; tile[r][cc + 3] = v.w;
  }
  __syncthreads();
#pragma unroll
  for (int p = 0; p < 4; p++) {
    int nn = cr + p * 16;
    f16x4 h;
    h[0] = (f16)tile[cc + 0][nn]; h[1] = (f16)tile[cc + 1][nn];
    h[2] = (f16)tile[cc + 2][nn]; h[3] = (f16)tile[cc + 3][nn];
    *(f16x4*)&dst[(size_t)(n0 + nn) * 1024 + k0 + cc] = h;
  }
}

// ---------- QKV GEMM: 256x256 tile, BK=64, 8-phase counted-vmcnt pipeline ----------
// 512 thr (8 waves, 2x4); per-wave C = {2 m-chunks of 64} x {2 n-chunks of 32}.
// LDS: 8 half-tile slots [par][mat][half] of 128x64 f16 = 128 KB. Raw barriers,
// vmcnt(4) checkpoints at ph4/ph8; slot ledger verified (see stage schedule below).
__global__ __launch_bounds__(512, 1) void k_gemm_qkv(const f16* __restrict__ A, const f16* __restrict__ wt,
                                                     const float* __restrict__ bq, const float* __restrict__ bk,
                                                     const float* __restrict__ bv,
                                                     f16* __restrict__ q, f16* __restrict__ k, f16* __restrict__ v) {
  __shared__ f16 L[8][128 * 64];
  const int t = threadIdx.x;
  const int lane = t & 63, wid = t >> 6;
  const int lr = lane & 15, lg = lane >> 4;
  const int wm = wid >> 2, wn = wid & 3;          // waves 2x4
  const int lrow = lane >> 3;
  const int cb = (((lane & 7) ^ lrow) << 4);      // pre-swizzled source byte col
  // XCD-aware: XCD x owns a 4bx x 6by panel rectangle (A 2MB + B 3MB ~ L2-fit).
  const int bid = blockIdx.x;                      // 192 blocks
  const int x = bid & 7, loc = bid >> 3;           // loc 0..23
  const int bx = (x & 3) * 4 + (loc & 3);          // 0..15
  const int by = (x >> 2) * 6 + (loc >> 2);        // 0..11
  const int m0 = bx * 256, n0 = by * 256;
  const f16* Ag = A + (size_t)m0 * 1024;
  const f16* Wr = wt + (size_t)n0 * 1024;
  const int zsel = by >> 2, cbs = (by & 3) * 256;
  const float* bias = (zsel == 0 ? bq : zsel == 1 ? bk : bv) + cbs;
  f16* dst = (zsel == 0 ? q : zsel == 1 ? k : v) + cbs;

  f32x4 acc[8][4] = {};

  // stage one half-tile (128 rows x 64 k): 2 gload16 per thread
  auto stageH = [&](int par, int mat, int h, int tk) {
    const f16* base = (mat ? Wr : Ag) + (size_t)(h * 128) * 1024 + (tk << 6);
    char* slot = (char*)&L[par * 4 + mat * 2 + h][0];
#pragma unroll
    for (int j = 0; j < 2; j++) {
      int rbase = j * 64 + wid * 8;               // wave-uniform
      gload16((const char*)&base[(size_t)(rbase + lrow) * 1024] + cb, slot + rbase * 128);
    }
  };
  auto loadA = [&](int par, int h, f16x8 (&af)[8]) {
    const char* S = (const char*)&L[par * 4 + h][0];
#pragma unroll
    for (int mt = 0; mt < 4; mt++) {
      int ra = wm * 64 + mt * 16 + lr;
#pragma unroll
      for (int kh = 0; kh < 2; kh++)
        af[mt * 2 + kh] = *(const f16x8*)(S + ra * 128 + ((kh * 64 + lg * 16) ^ ((lr & 7) << 4)));
    }
  };
  auto loadB = [&](int par, int h, f16x8 (&bf)[4]) {
    const char* S = (const char*)&L[par * 4 + 2 + h][0];
#pragma unroll
    for (int nt = 0; nt < 2; nt++) {
      int rb = wn * 32 + nt * 16 + lr;
#pragma unroll
      for (int kh = 0; kh < 2; kh++)
        bf[nt * 2 + kh] = *(const f16x8*)(S + rb * 128 + ((kh * 64 + lg * 16) ^ ((lr & 7) << 4)));
    }
  };
  auto mfma16 = [&](int mh, int nh, f16x8 (&af)[8], f16x8 (&bf)[4]) {
    __builtin_amdgcn_s_setprio(1);
#pragma unroll
    for (int kh = 0; kh < 2; kh++)
#pragma unroll
      for (int mt = 0; mt < 4; mt++)
#pragma unroll
        for (int nt = 0; nt < 2; nt++)
          acc[mh * 4 + mt][nh * 2 + nt] = MFMA(af[mt * 2 + kh], bf[nt * 2 + kh], acc[mh * 4 + mt][nh * 2 + nt]);
    __builtin_amdgcn_s_setprio(0);
  };

  // prologue: t0 {A0,B0,B1,A1}p0 + t1 {A0,B1,A1}p1 (B0p1 staged in-loop at ph1)
  stageH(0, 0, 0, 0); stageH(0, 1, 0, 0); stageH(0, 1, 1, 0); stageH(0, 0, 1, 0);
  stageH(1, 0, 0, 1); stageH(1, 1, 1, 1); stageH(1, 0, 1, 1);
  asm volatile("s_waitcnt vmcnt(6)" ::: "memory");   // t0 halves landed; t1's 3 may fly
  BARRAW();

  f16x8 afA[8], afB[8], bfA[4], bfB[4];
  for (int i = 0; i < 8; i++) {                    // 2 K-tiles per iter, 16 tiles total
    const int t2 = 2 * i + 2, t3 = 2 * i + 3;
    const bool pre = (i < 7);
    // ph1: quadrant (0,0) of even tile
    loadA(0, 0, afA); loadB(0, 0, bfA);
    stageH(1, 1, 0, 2 * i + 1);                    // B0p1 <- odd tile (read ph5/ph8)
    BARRAW(); WAITLGKM0();
    mfma16(0, 0, afA, bfA);
    BARRAW();
    // ph2: (0,1)
    loadB(0, 1, bfB);
    if (pre) stageH(0, 0, 0, t2);                  // A0p0
    BARRAW(); WAITLGKM0();
    mfma16(0, 1, afA, bfB);
    BARRAW();
    // ph3: (1,1)
    loadA(0, 1, afB);
    if (pre) stageH(0, 1, 1, t2);                  // B1p0
    BARRAW(); WAITLGKM0();
    mfma16(1, 1, afB, bfB);
    BARRAW();
    // ph4: (1,0)
    loadB(0, 0, bfA);                              // re-read B0p0 (still even tile)
    if (pre) stageH(0, 0, 1, t2);                  // A1p0
    asm volatile("s_waitcnt vmcnt(4)" ::: "memory");
    BARRAW(); WAITLGKM0();
    mfma16(1, 0, afB, bfA);
    BARRAW();
    // ph5: (0,0) of odd tile
    loadA(1, 0, afA); loadB(1, 0, bfA);
    if (pre) stageH(0, 1, 0, t2);                  // B0p0
    BARRAW(); WAITLGKM0();
    mfma16(0, 0, afA, bfA);
    BARRAW();
    // ph6: (0,1)
    loadB(1, 1, bfB);
    if (pre) stageH(1, 0, 0, t3);                  // A0p1
    BARRAW(); WAITLGKM0();
    mfma16(0, 1, afA, bfB);
    BARRAW();
    // ph7: (1,1)
    loadA(1, 1, afB);
    if (pre) stageH(1, 1, 1, t3);                  // B1p1
    BARRAW(); WAITLGKM0();
    mfma16(1, 1, afB, bfB);
    BARRAW();
    // ph8: (1,0)
    loadB(1, 0, bfA);
    if (pre) stageH(1, 0, 1, t3);                  // A1p1
    asm volatile("s_waitcnt vmcnt(4)" ::: "memory");
    BARRAW(); WAITLGKM0();
    mfma16(1, 0, afB, bfA);
    BARRAW();
  }

  // epilogue: rows m0 + mh*128 + wm*64 + mt*16 + lg*4 + e; cols nh*128 + wn*32 + nt*16 + lr
#pragma unroll
  for (int mh = 0; mh < 2; mh++)
#pragma unroll
    for (int mt = 0; mt < 4; mt++)
#pragma unroll
      for (int nh = 0; nh < 2; nh++)
#pragma unroll
        for (int nt = 0; nt < 2; nt++) {
          int col = nh * 128 + wn * 32 + nt * 16 + lr;
          float bcol = bias[col];
#pragma unroll
          for (int e = 0; e < 4; e++) {
            int row = m0 + mh * 128 + wm * 64 + mt * 16 + lg * 4 + e;
            dst[(size_t)row * 1024 + col] = (f16)(acc[mh * 4 + mt][nh * 2 + nt][e] + bcol);
          }
        }
}

// ---------- O-GEMM: 128x128 2-phase (kept) ----------
__global__ __launch_bounds__(256, 2) void k_gemm_o(const f16* __restrict__ A, const f16* __restrict__ Wrows3,
                                                   const float* __restrict__ bo, float* __restrict__ out) {
  __shared__ f16 Al[2][128 * 64];
  __shared__ f16 Bl[2][128 * 64];
  const int t = threadIdx.x;
  const int lane = t & 63, wid = t >> 6;
  const int lr = lane & 15, lg = lane >> 4;
  const int wm = wid >> 1, wn = wid & 1;
  const int lrow = lane >> 3;
  const int cb = (((lane & 7) ^ lrow) << 4);
  const int m0 = blockIdx.x * 128, n0 = blockIdx.y * 128;
  const f16* Wrows = Wrows3 + (size_t)n0 * 1024;
  const float* bias = bo + n0;
  float* of = out + n0;

  f32x4 acc[4][4] = {};

  auto stage = [&](int k0, int bs) {
#pragma unroll
    for (int it = 0; it < 4; it++) {
      int rbase = it * 32 + wid * 8;
      int row = rbase + lrow;
      gload16((const char*)&A[(size_t)(m0 + row) * 1024 + k0] + cb, (char*)&Al[bs][0] + rbase * 128);
      gload16((const char*)&Wrows[(size_t)row * 1024 + k0] + cb, (char*)&Bl[bs][0] + rbase * 128);
    }
  };

  stage(0, 0);
  __syncthreads();
  int cur = 0;
  for (int k0 = 0; k0 < 1024; k0 += 64) {
    if (k0 + 64 < 1024) stage(k0 + 64, cur ^ 1);
    f16x8 af[2][4], bf[2][4];
#pragma unroll
    for (int xx = 0; xx < 4; xx++) {
      int ra = wm * 64 + xx * 16 + lr;
      int rb = wn * 64 + xx * 16 + lr;
#pragma unroll
      for (int kh = 0; kh < 2; kh++) {
        int ca = (kh * 64 + lg * 16) ^ ((lr & 7) << 4);
        af[kh][xx] = *(const f16x8*)((char*)&Al[cur][0] + ra * 128 + ca);
        bf[kh][xx] = *(const f16x8*)((char*)&Bl[cur][0] + rb * 128 + ca);
      }
    }
    __builtin_amdgcn_s_setprio(1);
#pragma unroll
    for (int kh = 0; kh < 2; kh++)
#pragma unroll
      for (int mt = 0; mt < 4; mt++)
#pragma unroll
        for (int nt = 0; nt < 4; nt++)
          acc[mt][nt] = MFMA(af[kh][mt], bf[kh][nt], acc[mt][nt]);
    __builtin_amdgcn_s_setprio(0);
    __syncthreads();
    cur ^= 1;
  }
#pragma unroll
  for (int mt = 0; mt < 4; mt++) {
#pragma unroll
    for (int nt = 0; nt < 4; nt++) {
      int col = wn * 64 + nt * 16 + lr;
      float bcol = bias[col];
#pragma unroll
      for (int e = 0; e < 4; e++) {
        int row = m0 + wm * 64 + mt * 16 + lg * 4 + e;
        of[(size_t)row * 1024 + col] = acc[mt][nt][e] + bcol;
      }
    }
  }
}

// ---------- RMSNorm + interleaved RoPE (in-place on fp16 q/k), fp32 math ----------
__global__ __launch_bounds__(256) void k_normrope(f16* __restrict__ qh, f16* __restrict__ kh,
                                                  const float* __restrict__ gq, const float* __restrict__ gk,
                                                  const float* __restrict__ cs, const float* __restrict__ sn) {
  int row = blockIdx.x, which = blockIdx.y;
  f16* buf = which ? kh : qh;
  const float* g = which ? gk : gq;
  int t = threadIdx.x, c4 = t * 4;
  f16x4 xv = *(const f16x4*)&buf[(size_t)row * 1024 + c4];
  float x0 = xv[0], x1 = xv[1], x2 = xv[2], x3 = xv[3];
  float ss = x0 * x0 + x1 * x1 + x2 * x2 + x3 * x3;
#pragma unroll
  for (int off = 1; off < 64; off <<= 1) ss += __shfl_xor(ss, off);
  __shared__ float red[4];
  if ((t & 63) == 0) red[t >> 6] = ss;
  __syncthreads();
  float inv = rsqrtf((red[0] + red[1] + red[2] + red[3]) * (1.0f / 1024.0f) + 1e-6f);
  int tt = row & 2047;
  float4 cv = *(const float4*)&cs[(size_t)tt * 1024 + c4];
  float4 sv = *(const float4*)&sn[(size_t)tt * 1024 + c4];
  float4 gv = *(const float4*)&g[c4];
  float y0 = x0 * inv * gv.x, y1 = x1 * inv * gv.y, y2 = x2 * inv * gv.z, y3 = x3 * inv * gv.w;
  f16x4 ov;
  ov[0] = (f16)(y0 * cv.x - y1 * sv.x);
  ov[1] = (f16)(y1 * cv.y + y0 * sv.y);
  ov[2] = (f16)(y2 * cv.z - y3 * sv.z);
  ov[3] = (f16)(y3 * cv.w + y2 * sv.w);
  *(f16x4*)&buf[(size_t)row * 1024 + c4] = ov;
}

// ---------- V transpose: [b,t,h*64+dh] -> [b,h,dh,t] ----------
__global__ __launch_bounds__(256) void k_vtrans(const f16* __restrict__ vh, f16* __restrict__ vt) {
  __shared__ f16 tile[64][65];
  int t = threadIdx.x;
  int t0 = blockIdx.x * 64;
  int bh = blockIdx.y;
  int b = bh >> 4, h = bh & 15;
  int rr = t >> 3, c8 = (t & 7) * 8;
#pragma unroll
  for (int p = 0; p < 2; p++) {
    int r = p * 32 + rr;
    f16x8 v = *(const f16x8*)&vh[(size_t)(b * 2048 + t0 + r) * 1024 + h * 64 + c8];
#pragma unroll
    for (int j = 0; j < 8; j++) tile[r][c8 + j] = v[j];
  }
  __syncthreads();
#pragma unroll
  for (int p = 0; p < 2; p++) {
    int dh = p * 32 + rr;
    f16x8 o;
#pragma unroll
    for (int j = 0; j < 8; j++) o[j] = tile[c8 + j][dh];
    *(f16x8*)&vt[((size_t)bh * 64 + dh) * 2048 + t0 + c8] = o;
  }
}

// ---------- flash attention (R6): 32 q/wave, ones-column row-sum, dbuf ----------
#define ASWZ(row) ((((row) & 3) | (((row) & 8) >> 1)) << 4)

__global__ __launch_bounds__(256, 2) void k_attn(const f16* __restrict__ qh, const f16* __restrict__ kh,
                                                 const f16* __restrict__ vt, f16* __restrict__ ao) {
  __shared__ f16 Kl[2][64 * 64];
  __shared__ f16 Vl[2][64 * 64];
  const int t = threadIdx.x;
  const int lane = t & 63, wid = t >> 6;
  const int lr = lane & 15, lg = lane >> 4;
  const int lgb = lg << 4;
  const int raw = blockIdx.x;
  const int mybh = ((raw & 7) << 2) | ((raw >> 3) & 3);
  const int myq = raw >> 5;
  const int b = mybh >> 4, h = mybh & 15;
  const int q0 = myq * 128 + wid * 32;
  const f16* Qb = qh + ((size_t)(b * 2048 + q0)) * 1024 + h * 64;
  f16x8 qf[2][2];
#pragma unroll
  for (int g = 0; g < 2; g++) {
    qf[g][0] = *(const f16x8*)&Qb[(size_t)(g * 16 + lr) * 1024 + lg * 8];
    qf[g][1] = *(const f16x8*)&Qb[(size_t)(g * 16 + lr) * 1024 + 32 + lg * 8];
  }
  const f16* Kg = kh + ((size_t)b * 2048) * 1024 + h * 64;
  const f16* Vg = vt + ((size_t)mybh) * 64 * 2048;
  const int lrow = lane >> 3;
  const int sg = (lane & 7) << 4;
  const float sc = 0.125f * 1.44269504088896340736f;
  float m[2] = {-1e30f, -1e30f};
  f32x4 acc[2][4] = {};
  f32x4 accl[2] = {};
  const f16 ov1 = (lr == 0) ? (f16)1.0f : (f16)0.0f;
  const f16x8 onesf = {ov1, ov1, ov1, ov1, ov1, ov1, ov1, ov1};

  auto stage = [&](int kvo, int bs) {
#pragma unroll
    for (int i = 0; i < 2; i++) {
      int rbase = (i * 4 + wid) * 8;
      int row = rbase + lrow;
      int cswz = sg ^ ASWZ(row);
      gload16((const char*)(Kg + (size_t)(kvo + row) * 1024) + cswz, (char*)&Kl[bs][0] + rbase * 128);
      gload16((const char*)(Vg + (size_t)row * 2048 + kvo) + cswz, (char*)&Vl[bs][0] + rbase * 128);
    }
  };

  stage(0, 0);
  __syncthreads();
  int cur = 0;

  for (int kv0 = 0; kv0 < 2048; kv0 += 64) {
    if (kv0 + 64 < 2048) stage(kv0 + 64, cur ^ 1);
    const char* Kb = (const char*)&Kl[cur][0];
    const char* Vb = (const char*)&Vl[cur][0];

    f32x4 s[2][4];
    __builtin_amdgcn_s_setprio(1);
#pragma unroll
    for (int ks = 0; ks < 4; ks++) {
      int key = ((lr >> 2) << 3) + (lr & 3) + ((ks & 1) << 2) + ((ks >> 1) << 5);
      int sw = ASWZ(key);
      f16x8 kf0 = *(const f16x8*)(Kb + key * 128 + (lgb ^ sw));
      f16x8 kf1 = *(const f16x8*)(Kb + key * 128 + ((64 + lgb) ^ sw));
#pragma unroll
      for (int g = 0; g < 2; g++) {
        f32x4 z = {};
        z = MFMA(kf0, qf[g][0], z);
        z = MFMA(kf1, qf[g][1], z);
        s[g][ks] = z;
      }
    }
    __builtin_amdgcn_s_setprio(0);

    union U { f16x8 v; f16x2 h[4]; } u[2][2];
#pragma unroll
    for (int g = 0; g < 2; g++) {
      float smax = fmaxf(fmaxf(s[g][0][0], s[g][0][1]), s[g][0][2]);
      smax = fmaxf(fmaxf(smax, s[g][0][3]), s[g][1][0]);
      smax = fmaxf(fmaxf(smax, s[g][1][1]), s[g][1][2]);
      smax = fmaxf(fmaxf(smax, s[g][1][3]), s[g][2][0]);
      smax = fmaxf(fmaxf(smax, s[g][2][1]), s[g][2][2]);
      smax = fmaxf(fmaxf(smax, s[g][2][3]), s[g][3][0]);
      smax = fmaxf(fmaxf(smax, s[g][3][1]), s[g][3][2]);
      smax = fmaxf(smax, s[g][3][3]);
      smax = fmaxf(smax, __shfl_xor(smax, 16));
      smax = fmaxf(smax, __shfl_xor(smax, 32));
      float smc = smax * sc;

      if (!__all(smc - m[g] <= 8.f)) {
        float mn = fmaxf(m[g], smc);
        float al = exp2f(m[g] - mn);
        m[g] = mn;
        float alq[4];
#pragma unroll
        for (int e = 0; e < 4; e++) alq[e] = __shfl(al, lg * 4 + e);
#pragma unroll
        for (int ds = 0; ds < 4; ds++)
#pragma unroll
          for (int e = 0; e < 4; e++) acc[g][ds][e] *= alq[e];
#pragma unroll
        for (int e = 0; e < 4; e++) accl[g][e] *= alq[e];
      }

#pragma unroll
      for (int ks = 0; ks < 4; ks++) {
        float p0 = exp2f(fmaf(s[g][ks][0], sc, -m[g]));
        float p1 = exp2f(fmaf(s[g][ks][1], sc, -m[g]));
        float p2 = exp2f(fmaf(s[g][ks][2], sc, -m[g]));
        float p3 = exp2f(fmaf(s[g][ks][3], sc, -m[g]));
        u[g][ks >> 1].h[(ks & 1) * 2 + 0] = PKRTZ(p0, p1);
        u[g][ks >> 1].h[(ks & 1) * 2 + 1] = PKRTZ(p2, p3);
      }
    }

    __builtin_amdgcn_s_setprio(1);
#pragma unroll
    for (int ds = 0; ds < 4; ds++) {
      int vrow = ds * 16 + lr;
      int sw = ASWZ(vrow);
      f16x8 vf0 = *(const f16x8*)(Vb + vrow * 128 + (lgb ^ sw));
      f16x8 vf1 = *(const f16x8*)(Vb + vrow * 128 + ((64 + lgb) ^ sw));
#pragma unroll
      for (int g = 0; g < 2; g++) {
        acc[g][ds] = MFMA(u[g][0].v, vf0, acc[g][ds]);
        acc[g][ds] = MFMA(u[g][1].v, vf1, acc[g][ds]);
      }
    }
#pragma unroll
    for (int g = 0; g < 2; g++) {
      accl[g] = MFMA(u[g][0].v, onesf, accl[g]);
      accl[g] = MFMA(u[g][1].v, onesf, accl[g]);
    }
    __builtin_amdgcn_s_setprio(0);

    __syncthreads();
    cur ^= 1;
  }

#pragma unroll
  for (int g = 0; g < 2; g++) {
#pragma unroll
    for (int e = 0; e < 4; e++) {
      float lf = 1.f / __shfl(accl[g][e], lg << 4);
      size_t row = (size_t)(b * 2048 + q0 + g * 16 + lg * 4 + e);
#pragma unroll
      for (int ds = 0; ds < 4; ds++)
        ao[row * 1024 + h * 64 + ds * 16 + lr] = (f16)(acc[g][ds][e] * lf);
    }
  }
}

extern "C" void kernel_launch(void* const* d_in, const int* in_sizes, int n_in,
                              void* d_out, int out_size, void* d_ws, size_t ws_size,
                              hipStream_t stream) {
  const float* hid  = (const float*)d_in[0];
  const float* cosb = (const float*)d_in[1];
  const float* sinb = (const float*)d_in[2];
  const float* wq = (const float*)d_in[3];
  const float* bq = (const float*)d_in[4];
  const float* wk = (const float*)d_in[5];
  const float* bk = (const float*)d_in[6];
  const float* wv = (const float*)d_in[7];
  const float* bv = (const float*)d_in[8];
  const float* gq = (const float*)d_in[9];
  const float* gk = (const float*)d_in[10];
  const float* wo = (const float*)d_in[11];
  const float* bo = (const float*)d_in[12];
  float* out = (float*)d_out;

  char* ws = (char*)d_ws;
  f16* aH  = (f16*)(ws);                          // 8 MB: hidden fp16 [4096][1024]
  f16* wt  = (f16*)(ws + ((size_t)8 << 20));      // 8 MB: 4 weights transposed [n][k] fp16
  f16* qh  = (f16*)(ws + ((size_t)16 << 20));     // 8 MB
  f16* khb = (f16*)(ws + ((size_t)24 << 20));     // 8 MB
  f16* vhb = (f16*)(ws + ((size_t)32 << 20));     // 8 MB
  f16* vtb = (f16*)(ws + ((size_t)40 << 20));     // 8 MB: V^T [b,h,dh,t]
  f16* ao  = (f16*)(ws + ((size_t)48 << 20));     // 8 MB: attention out [4096][1024]

  k_cvt_hidden<<<dim3(4096), dim3(256), 0, stream>>>(hid, aH);
  k_cvt_w<<<dim3(16, 16, 4), dim3(256), 0, stream>>>(wq, wk, wv, wo, wt);
  k_gemm_qkv<<<dim3(192), dim3(512), 0, stream>>>(aH, wt, bq, bk, bv, qh, khb, vhb);
  k_normrope<<<dim3(4096, 2), dim3(256), 0, stream>>>(qh, khb, gq, gk, cosb, sinb);
  k_vtrans<<<dim3(32, 32), dim3(256), 0, stream>>>(vhb, vtb);
  k_attn<<<dim3(512), dim3(256), 0, stream>>>(qh, khb, vtb, ao);
  k_gemm_o<<<dim3(32, 8), dim3(256), 0, stream>>>(ao, wt + (size_t)3 * 1024 * 1024, bo, out);
}